// Round 5
// baseline (109.393 us; speedup 1.0000x reference)
//
#include <hip/hip_runtime.h>
#include <hip/hip_bf16.h>

// Problem constants: D=16, N=512, M_HID=5, BATCH=1024
#define D_  16
#define N_  512
#define MH  5
#define B_  1024

// Table: 64 knots per (d,n) over x in [-5,5]; h = 10/63.
#define KP   64
#define KPM1 63
#define XMIN -5.0f
#define XSCALE (63.0f / 10.0f)   /* knots per x-unit */

// Packed per-d param slot layout (floats):
//  [0..4] t0=sp10(w0)  [5..9] b0   [10..14] tanh(a0)
//  [15..39] t1=sp10(w1)[40..44] b1 [45..49] tanh(a1)
//  [50..74] t2=sp10(w2)[75..79] b2 [80..84] tanh(a2)
//  [85..89] t3=sp10(w3)[90] b3
#define PSTRIDE 96

__device__ __forceinline__ float ftanh(float x) {
    float e = __expf(2.0f * x);
    return 1.0f - __fdividef(2.0f, 1.0f + e);
}
__device__ __forceinline__ float sp10(float x) {
    float t = 10.0f * x;
    return (t > 20.0f) ? x : 0.1f * __logf(1.0f + __expf(t));
}
__device__ __forceinline__ float sp1(float x) {
    return (x > 20.0f) ? x : __logf(1.0f + __expf(x));
}

// ---------------- Kernel A: fused prep + table build + eval ----------------
// One block per component n (512 blocks x 256 threads).
// Phase 1: load+transform this n's params for all 16 d into LDS.
// Phase 2: build the 16x64 table f_{d,n}(x_j)=log(phidot+1e-10) in LDS
//          (4 chains/thread; lanes of a wave share d -> broadcast param reads).
// Phase 3: each thread evaluates 4 batch rows m (16 lerps each), writes S[m][n].
__global__ __launch_bounds__(256) void fused_kernel(
    const float* __restrict__ X,
    const float* __restrict__ w0, const float* __restrict__ b0, const float* __restrict__ a0,
    const float* __restrict__ w1, const float* __restrict__ b1, const float* __restrict__ a1,
    const float* __restrict__ w2, const float* __restrict__ b2, const float* __restrict__ a2,
    const float* __restrict__ w3, const float* __restrict__ b3,
    float* __restrict__ S)
{
    __shared__ float w[D_][PSTRIDE];   // 6 KB params
    __shared__ float q[D_][KP];        // 4 KB table
    const int n = blockIdx.x;
    const int t = threadIdx.x;

    // ---- Phase 1: params -> LDS (16*91 = 1456 slots) ----
    for (int i = t; i < D_ * 91; i += 256) {
        int d = i / 91;
        int s = i - d * 91;
        int dn = d * N_ + n;            // source tensors are [D][N][...]
        float v;
        if      (s <  5) v = sp10 (w0[dn *  5 + s      ]);
        else if (s < 10) v =       b0[dn *  5 + s -  5 ];
        else if (s < 15) v = ftanh(a0[dn *  5 + s - 10 ]);
        else if (s < 40) v = sp10 (w1[dn * 25 + s - 15 ]);
        else if (s < 45) v =       b1[dn *  5 + s - 40 ];
        else if (s < 50) v = ftanh(a1[dn *  5 + s - 45 ]);
        else if (s < 75) v = sp10 (w2[dn * 25 + s - 50 ]);
        else if (s < 80) v =       b2[dn *  5 + s - 75 ];
        else if (s < 85) v = ftanh(a2[dn *  5 + s - 80 ]);
        else if (s < 90) v = sp10 (w3[dn *  5 + s - 85 ]);
        else             v =       b3[dn];
        w[d][s] = v;
    }
    __syncthreads();

    // ---- Phase 2: build table (4 chains per thread, wave-uniform d) ----
    #pragma unroll
    for (int g = 0; g < 4; g++) {
        const int idx = t + 256 * g;        // 0..1023
        const int d = idx >> 6;             // uniform across a 64-lane wave
        const int j = idx & 63;
        const float* wp = w[d];
        const float xv = fmaf((float)j, 10.0f / (float)KPM1, XMIN);

        float phi[MH], pdot[MH];
        #pragma unroll
        for (int l = 0; l < MH; l++) {
            float tw = wp[l];
            float z  = fmaf(xv, tw, wp[5 + l]);
            float tz = ftanh(z);
            float ta = wp[10 + l];
            float gate = fmaf(ta, fmaf(-tz, tz, 1.0f), 1.0f);
            pdot[l] = tw * gate;
            phi[l]  = fmaf(tz, ta, z);
        }
        #pragma unroll
        for (int layer = 0; layer < 2; layer++) {
            const int wb = 15 + layer * 35;
            float zn[MH], pn[MH];
            #pragma unroll
            for (int l = 0; l < MH; l++) {
                float z   = wp[wb + 25 + l];
                float pdn = 0.0f;
                #pragma unroll
                for (int k = 0; k < MH; k++) {
                    float ww = wp[wb + k * MH + l];
                    z   = fmaf(phi[k],  ww, z);
                    pdn = fmaf(pdot[k], ww, pdn);
                }
                float tz = ftanh(z);
                float ta = wp[wb + 30 + l];
                float gate = fmaf(ta, fmaf(-tz, tz, 1.0f), 1.0f);
                pn[l] = pdn * gate;
                zn[l] = fmaf(tz, ta, z);
            }
            #pragma unroll
            for (int l = 0; l < MH; l++) { phi[l] = zn[l]; pdot[l] = pn[l]; }
        }
        float z = wp[90], pdn = 0.0f;
        #pragma unroll
        for (int k = 0; k < MH; k++) {
            float ww = wp[85 + k];
            z   = fmaf(phi[k],  ww, z);
            pdn = fmaf(pdot[k], ww, pdn);
        }
        float e = __expf(-z);
        float sg = __fdividef(1.0f, 1.0f + e);
        float p = pdn * sg * (1.0f - sg);
        q[d][j] = __logf(p + 1e-10f);
    }
    __syncthreads();

    // ---- Phase 3: evaluate 4 batch rows per thread ----
    #pragma unroll
    for (int i = 0; i < 4; i++) {
        const int m = t + 256 * i;
        float x[D_];
        const float4* xr = (const float4*)(X + m * D_);
        #pragma unroll
        for (int k = 0; k < 4; k++) {
            float4 v = xr[k];
            x[4*k+0] = v.x; x[4*k+1] = v.y; x[4*k+2] = v.z; x[4*k+3] = v.w;
        }
        float acc = 0.0f;
        #pragma unroll
        for (int d = 0; d < D_; d++) {
            float xi = fmaf(x[d], XSCALE, -XMIN * XSCALE);
            xi = fminf(fmaxf(xi, 0.0f), (float)KPM1 - 0.01f);
            int j = (int)xi;
            float fr = xi - (float)j;
            float f0 = q[d][j];
            float f1 = q[d][j + 1];
            acc += fmaf(fr, f1 - f0, f0);
        }
        S[(size_t)m * N_ + n] = acc;   // [m][n] layout -> coalesced reduce
    }
}

// ---------------- Kernel B: per-m weighted logsumexp over n ----------------
__global__ __launch_bounds__(256) void reduce_kernel(
    const float* __restrict__ S, const float* __restrict__ amix, float* __restrict__ out)
{
    const int m = blockIdx.x;
    const int t = threadIdx.x;
    const float* row = S + (size_t)m * N_;

    float sa = row[t];
    float sb = row[t + 256];
    float mx = fmaxf(sa, sb);
    #pragma unroll
    for (int o = 32; o; o >>= 1) mx = fmaxf(mx, __shfl_xor(mx, o));

    __shared__ float rmax[4], rs1[4], rs2[4];
    if ((t & 63) == 0) rmax[t >> 6] = mx;
    __syncthreads();
    const float M = fmaxf(fmaxf(rmax[0], rmax[1]), fmaxf(rmax[2], rmax[3]));

    float wa = sp1(amix[t]);
    float wb = sp1(amix[t + 256]);
    float psum = wa + wb;
    float pexp = fmaf(wa, __expf(sa - M), wb * __expf(sb - M));
    #pragma unroll
    for (int o = 32; o; o >>= 1) {
        psum += __shfl_xor(psum, o);
        pexp += __shfl_xor(pexp, o);
    }
    if ((t & 63) == 0) { rs1[t >> 6] = psum; rs2[t >> 6] = pexp; }
    __syncthreads();
    if (t == 0) {
        float s1 = rs1[0] + rs1[1] + rs1[2] + rs1[3];
        float s2 = rs2[0] + rs2[1] + rs2[2] + rs2[3];
        float f  = __fdividef(s2, s1);
        out[m] = __logf(f + 1e-10f) + M;
    }
}

extern "C" void kernel_launch(void* const* d_in, const int* in_sizes, int n_in,
                              void* d_out, int out_size, void* d_ws, size_t ws_size,
                              hipStream_t stream) {
    const float* X    = (const float*)d_in[0];
    const float* w0   = (const float*)d_in[1];
    const float* b0   = (const float*)d_in[2];
    const float* a0   = (const float*)d_in[3];
    const float* w1   = (const float*)d_in[4];
    const float* b1   = (const float*)d_in[5];
    const float* a1   = (const float*)d_in[6];
    const float* w2   = (const float*)d_in[7];
    const float* b2   = (const float*)d_in[8];
    const float* a2   = (const float*)d_in[9];
    const float* w3   = (const float*)d_in[10];
    const float* b3   = (const float*)d_in[11];
    const float* amix = (const float*)d_in[12];
    float* out = (float*)d_out;

    float* S = (float*)d_ws;   // 1024*512*4 = 2.10 MB

    fused_kernel<<<N_, 256, 0, stream>>>(X, w0, b0, a0, w1, b1, a1,
                                         w2, b2, a2, w3, b3, S);
    reduce_kernel<<<B_, 256, 0, stream>>>(S, amix, out);
}

// Round 6
// 101.764 us; speedup vs baseline: 1.0750x; 1.0750x over previous
//
#include <hip/hip_runtime.h>
#include <hip/hip_bf16.h>

// Problem constants: D=16, N=512, M_HID=5, BATCH=1024
#define D_  16
#define N_  512
#define MH  5
#define B_  1024

// Table: 64 knots per (d,n) over x in [-5,5]; h = 10/63.
#define KP   64
#define KPM1 63
#define XMIN -5.0f
#define XSCALE (63.0f / 10.0f)   /* knots per x-unit */

// Packed per-(d,n) param slot layout (floats):
//  [0..4] t0=sp10(w0)  [5..9] b0   [10..14] tanh(a0)
//  [15..39] t1=sp10(w1)[40..44] b1 [45..49] tanh(a1)
//  [50..74] t2=sp10(w2)[75..79] b2 [80..84] tanh(a2)
//  [85..89] t3=sp10(w3)[90] b3
#define PSTRIDE 96
#define DN_PER_BLK 4

__device__ __forceinline__ float ftanh(float x) {
    float e = __expf(2.0f * x);
    return 1.0f - __fdividef(2.0f, 1.0f + e);
}
__device__ __forceinline__ float sp10(float x) {
    float t = 10.0f * x;
    return (t > 20.0f) ? x : 0.1f * __logf(1.0f + __expf(t));
}
__device__ __forceinline__ float sp1(float x) {
    return (x > 20.0f) ? x : __logf(1.0f + __expf(x));
}

// ---------------- Kernel A: fused prep + table build ----------------
// 2048 blocks x 256 threads; each block handles 4 (n,d) slots.
// Thread t: slot group g=t>>6 (wave-uniform), knot j=t&63.
// T[dn][64] layout, dn = n*16+d; writes fully coalesced.
// NOTE (round-5 lesson): do NOT fuse this with eval into 512 blocks —
// 2 blocks/CU cannot hide the scattered param-load latency (−10 us measured).
__global__ __launch_bounds__(256) void table_kernel(
    const float* __restrict__ w0, const float* __restrict__ b0, const float* __restrict__ a0,
    const float* __restrict__ w1, const float* __restrict__ b1, const float* __restrict__ a1,
    const float* __restrict__ w2, const float* __restrict__ b2, const float* __restrict__ a2,
    const float* __restrict__ w3, const float* __restrict__ b3,
    float* __restrict__ T)
{
    __shared__ float w[DN_PER_BLK][PSTRIDE];
    const int t = threadIdx.x;

    // Load+transform params for the block's 4 dn slots.
    for (int i = t; i < DN_PER_BLK * 91; i += 256) {
        int local = i / 91;
        int s     = i - local * 91;
        int dng   = blockIdx.x * DN_PER_BLK + local;   // n*16 + d
        int n = dng >> 4;
        int d = dng & 15;
        int dn = d * N_ + n;                            // source tensors are [D][N][...]
        float v;
        if      (s <  5) v = sp10 (w0[dn *  5 + s      ]);
        else if (s < 10) v =       b0[dn *  5 + s -  5 ];
        else if (s < 15) v = ftanh(a0[dn *  5 + s - 10 ]);
        else if (s < 40) v = sp10 (w1[dn * 25 + s - 15 ]);
        else if (s < 45) v =       b1[dn *  5 + s - 40 ];
        else if (s < 50) v = ftanh(a1[dn *  5 + s - 45 ]);
        else if (s < 75) v = sp10 (w2[dn * 25 + s - 50 ]);
        else if (s < 80) v =       b2[dn *  5 + s - 75 ];
        else if (s < 85) v = ftanh(a2[dn *  5 + s - 80 ]);
        else if (s < 90) v = sp10 (w3[dn *  5 + s - 85 ]);
        else             v =       b3[dn];
        w[local][s] = v;
    }
    __syncthreads();

    const int g = t >> 6;          // wave-uniform -> LDS broadcast reads
    const int j = t & 63;
    const float* wp = w[g];
    const float xv = fmaf((float)j, 10.0f / (float)KPM1, XMIN);

    float phi[MH], pdot[MH];

    // layer 0 (input width 1, phidot_in = 1)
    #pragma unroll
    for (int l = 0; l < MH; l++) {
        float tw = wp[l];
        float z  = fmaf(xv, tw, wp[5 + l]);
        float tz = ftanh(z);
        float ta = wp[10 + l];
        float gate = fmaf(ta, fmaf(-tz, tz, 1.0f), 1.0f);
        pdot[l] = tw * gate;
        phi[l]  = fmaf(tz, ta, z);
    }

    // layers 1 and 2 (5x5)
    #pragma unroll
    for (int layer = 0; layer < 2; layer++) {
        const int wb = 15 + layer * 35;
        float zn[MH], pn[MH];
        #pragma unroll
        for (int l = 0; l < MH; l++) {
            float z   = wp[wb + 25 + l];
            float pdn = 0.0f;
            #pragma unroll
            for (int k = 0; k < MH; k++) {
                float ww = wp[wb + k * MH + l];
                z   = fmaf(phi[k],  ww, z);
                pdn = fmaf(pdot[k], ww, pdn);
            }
            float tz = ftanh(z);
            float ta = wp[wb + 30 + l];
            float gate = fmaf(ta, fmaf(-tz, tz, 1.0f), 1.0f);
            pn[l] = pdn * gate;
            zn[l] = fmaf(tz, ta, z);
        }
        #pragma unroll
        for (int l = 0; l < MH; l++) { phi[l] = zn[l]; pdot[l] = pn[l]; }
    }

    // layer 3 (5 -> 1), sigmoid derivative
    float z = wp[90], pdn = 0.0f;
    #pragma unroll
    for (int k = 0; k < MH; k++) {
        float ww = wp[85 + k];
        z   = fmaf(phi[k],  ww, z);
        pdn = fmaf(pdot[k], ww, pdn);
    }
    float e = __expf(-z);
    float s = __fdividef(1.0f, 1.0f + e);
    float p = pdn * s * (1.0f - s);
    T[(size_t)blockIdx.x * 256 + t] = __logf(p + 1e-10f);
}

// ---------------- Kernel B: table-lookup evaluation ----------------
// blockIdx = n*4 + mc; block stages the 4KB table for n, each thread
// does 16 lerps (one per d) and writes S[m][n].
__global__ __launch_bounds__(256) void eval_kernel(
    const float* __restrict__ X, const float* __restrict__ T, float* __restrict__ S)
{
    __shared__ float q[D_ * KP];   // 4 KB
    const int n   = blockIdx.x >> 2;
    const int mc  = blockIdx.x & 3;
    const int tid = threadIdx.x;

    ((float4*)q)[tid] = ((const float4*)(T + ((size_t)n << 10)))[tid];

    const int m = mc * 256 + tid;
    float x[D_];
    const float4* xr = (const float4*)(X + m * D_);
    #pragma unroll
    for (int i = 0; i < 4; i++) {
        float4 v = xr[i];
        x[4*i+0] = v.x; x[4*i+1] = v.y; x[4*i+2] = v.z; x[4*i+3] = v.w;
    }
    __syncthreads();

    float acc = 0.0f;
    #pragma unroll
    for (int d = 0; d < D_; d++) {
        float xi = fmaf(x[d], XSCALE, -XMIN * XSCALE);
        xi = fminf(fmaxf(xi, 0.0f), (float)KPM1 - 0.01f);
        int j = (int)xi;
        float fr = xi - (float)j;
        const float* row = q + (d << 6) + j;
        float f0 = row[0];
        float f1 = row[1];
        acc += fmaf(fr, f1 - f0, f0);
    }
    S[(size_t)m * N_ + n] = acc;   // [m][n] layout -> coalesced reduce
}

// ---------------- Kernel C: per-m weighted logsumexp over n ----------------
__global__ __launch_bounds__(256) void reduce_kernel(
    const float* __restrict__ S, const float* __restrict__ amix, float* __restrict__ out)
{
    const int m = blockIdx.x;
    const int t = threadIdx.x;
    const float* row = S + (size_t)m * N_;

    float sa = row[t];
    float sb = row[t + 256];
    float mx = fmaxf(sa, sb);
    #pragma unroll
    for (int o = 32; o; o >>= 1) mx = fmaxf(mx, __shfl_xor(mx, o));

    __shared__ float rmax[4], rs1[4], rs2[4];
    if ((t & 63) == 0) rmax[t >> 6] = mx;
    __syncthreads();
    const float M = fmaxf(fmaxf(rmax[0], rmax[1]), fmaxf(rmax[2], rmax[3]));

    float wa = sp1(amix[t]);
    float wb = sp1(amix[t + 256]);
    float psum = wa + wb;
    float pexp = fmaf(wa, __expf(sa - M), wb * __expf(sb - M));
    #pragma unroll
    for (int o = 32; o; o >>= 1) {
        psum += __shfl_xor(psum, o);
        pexp += __shfl_xor(pexp, o);
    }
    if ((t & 63) == 0) { rs1[t >> 6] = psum; rs2[t >> 6] = pexp; }
    __syncthreads();
    if (t == 0) {
        float s1 = rs1[0] + rs1[1] + rs1[2] + rs1[3];
        float s2 = rs2[0] + rs2[1] + rs2[2] + rs2[3];
        float f  = __fdividef(s2, s1);
        out[m] = __logf(f + 1e-10f) + M;
    }
}

extern "C" void kernel_launch(void* const* d_in, const int* in_sizes, int n_in,
                              void* d_out, int out_size, void* d_ws, size_t ws_size,
                              hipStream_t stream) {
    const float* X    = (const float*)d_in[0];
    const float* w0   = (const float*)d_in[1];
    const float* b0   = (const float*)d_in[2];
    const float* a0   = (const float*)d_in[3];
    const float* w1   = (const float*)d_in[4];
    const float* b1   = (const float*)d_in[5];
    const float* a1   = (const float*)d_in[6];
    const float* w2   = (const float*)d_in[7];
    const float* b2   = (const float*)d_in[8];
    const float* a2   = (const float*)d_in[9];
    const float* w3   = (const float*)d_in[10];
    const float* b3   = (const float*)d_in[11];
    const float* amix = (const float*)d_in[12];
    float* out = (float*)d_out;

    float* T = (float*)d_ws;                   // 8192*64*4  = 2.10 MB
    float* S = T + (size_t)D_ * N_ * KP;       // 1024*512*4 = 2.10 MB

    table_kernel<<<(D_ * N_) / DN_PER_BLK, 256, 0, stream>>>(
        w0, b0, a0, w1, b1, a1, w2, b2, a2, w3, b3, T);
    eval_kernel<<<N_ * 4, 256, 0, stream>>>(X, T, S);
    reduce_kernel<<<B_, 256, 0, stream>>>(S, amix, out);
}